// Round 18
// baseline (613.926 us; speedup 1.0000x reference)
//
#include <hip/hip_runtime.h>
#include <hip/hip_bf16.h>
#include <cstddef>

#define BB 16
#define TT 32
#define VV 1003
#define EE 100
#define HH 2048
#define G4 8192  // 4*H

typedef __attribute__((ext_vector_type(4))) float f32x4;
typedef unsigned char u8;

#define SA 64.0f        // A-side (x, h) scale
#define SB 128.0f       // B-side (W, U) scale
#define DESCALE 1.220703125e-4f  // 1/8192

__device__ __forceinline__ unsigned pk_lo(unsigned old, float a, float b) {
  return (unsigned)__builtin_amdgcn_cvt_pk_fp8_f32(a, b, (int)old, false);
}
__device__ __forceinline__ unsigned pk_hi(unsigned old, float a, float b) {
  return (unsigned)__builtin_amdgcn_cvt_pk_fp8_f32(a, b, (int)old, true);
}
__device__ __forceinline__ u8 cvt1fp8(float a) {
  return (u8)(__builtin_amdgcn_cvt_pk_fp8_f32(a, 0.f, 0, false) & 0xff);
}
__device__ __forceinline__ long mklong(unsigned lo, unsigned hi) {
  return (long)(((unsigned long long)hi << 32) | lo);
}

// ---------------- embedding gather -> fp8 A-fragments (pair-interleaved) -----
__global__ __launch_bounds__(256) void embed_frag(
    const int* __restrict__ tokens, const float* __restrict__ emb,
    u8* __restrict__ xf) {
  int i = blockIdx.x * 256 + threadIdx.x;   // 32t * 16b * 128e
  if (i >= TT * BB * 128) return;
  int e = i & 127, b = (i >> 7) & 15, t = i >> 11;
  float v = 0.f;
  if (e < EE) v = emb[(size_t)tokens[b * TT + t] * EE + e] * SA;
  int kt = e >> 5, kk = e & 31;
  int lane = (kk >> 3) * 16 + b, j = kk & 7;
  xf[(size_t)t * 2048 + (size_t)(kt >> 1) * 1024 + lane * 16 + (kt & 1) * 8 + j] =
      cvt1fp8(v);
}

// ---------------- split body (256 thr): R15 structure ------------------------
// LDS bytes: addr(c,row) = c*72 + (c>>6)*8 + row  (c in [0,256), row in [0,64))
__device__ __forceinline__ void split_body(
    u8* __restrict__ ldb,
    const float* __restrict__ src, u8* __restrict__ dst,
    int Kreal, int nkt2, int pair, int ct0, int tid) {
  int r0 = pair * 64;
#pragma unroll
  for (int p = 0; p < 4; p++) {
    int c4 = tid & 63, rq = p * 4 + (tid >> 6);
    int c = c4 * 4;
    int g = c >> 6;
    int rel = c & 63;
    int row = rq * 4;
    float4 v[4];
#pragma unroll
    for (int i = 0; i < 4; i++) {
      int r = r0 + row + i;
      v[i] = (r < Kreal)
          ? *(const float4*)&src[(size_t)r * G4 + (size_t)g * HH + ct0 * 4 + rel]
          : make_float4(0.f, 0.f, 0.f, 0.f);
    }
#pragma unroll
    for (int j = 0; j < 4; j++) {
      unsigned w = 0;
      w = pk_lo(w, ((const float*)&v[0])[j] * SB, ((const float*)&v[1])[j] * SB);
      w = pk_hi(w, ((const float*)&v[2])[j] * SB, ((const float*)&v[3])[j] * SB);
      int cc = c + j;
      *(unsigned*)&ldb[cc * 72 + g * 8 + row] = w;
    }
  }
  __syncthreads();
  int L = tid & 63;
  int cl = L & 15, gg = cl >> 2, hq = cl & 3;
  int row0 = (L >> 4) * 8;
#pragma unroll
  for (int pass = 0; pass < 4; pass++) {
    int ctr = (tid >> 6) + pass * 4;
    int cc = gg * 64 + ctr * 4 + hq;
    const u8* bp = &ldb[cc * 72 + gg * 8];
    uint2 h0 = *(const uint2*)&bp[row0];
    uint2 h1 = *(const uint2*)&bp[32 + row0];
    *(uint4*)&dst[((size_t)(ct0 + ctr) * nkt2 + pair) * 1024 + L * 16] =
        make_uint4(h0.x, h0.y, h1.x, h1.y);
  }
}

// ---------------- mega split: all six matrices in one dispatch ---------------
// grid (162, 32): bx in [0,2) W0 | [2,34) U0 | [34,66) W1 | [66,98) U1 |
// [98,130) W2 | [130,162) U2.  by*16 = ct group.
__global__ __launch_bounds__(256) void split_all(
    const float* __restrict__ W0, u8* __restrict__ wf0,
    const float* __restrict__ U0, u8* __restrict__ uf0,
    const float* __restrict__ W1, u8* __restrict__ wf1,
    const float* __restrict__ U1, u8* __restrict__ uf1,
    const float* __restrict__ W2, u8* __restrict__ wf2,
    const float* __restrict__ U2, u8* __restrict__ uf2) {
  __shared__ __align__(16) u8 ldb[256 * 72 + 16];   // 18.5 KB
  int tid = threadIdx.x;
  int bx = blockIdx.x, ct0 = blockIdx.y * 16;
  if (bx < 2)        split_body(ldb, W0, wf0, EE, 2,  bx,        ct0, tid);
  else if (bx < 34)  split_body(ldb, U0, uf0, HH, 32, bx - 2,    ct0, tid);
  else if (bx < 66)  split_body(ldb, W1, wf1, HH, 32, bx - 34,   ct0, tid);
  else if (bx < 98)  split_body(ldb, U1, uf1, HH, 32, bx - 66,   ct0, tid);
  else if (bx < 130) split_body(ldb, W2, wf2, HH, 32, bx - 98,   ct0, tid);
  else               split_body(ldb, U2, uf2, HH, 32, bx - 130,  ct0, tid);
}

// ---------------- MFMA fp8 GEMM + zero-init of recurrence state --------------
__global__ __launch_bounds__(512) void gemm_mfma(
    const u8* __restrict__ af, int t_stride, int nkt2,
    const u8* __restrict__ wfrag, const float* __restrict__ bias,
    float* __restrict__ xz,
    unsigned* __restrict__ hzero,    // allhf[layer] slot 0: 32768 B
    unsigned* __restrict__ hcz) {    // hT0 + c: 262144 B
  __shared__ __align__(16) u8 Bs[3][8][1024];  // 24 KB
  int tid = threadIdx.x;
  int w = tid >> 6, L = tid & 63;
  int ct0 = blockIdx.x * 8;
  int t_a = blockIdx.y * 4 + (w & 3);
  int nt0 = (w >> 2) * 4;

  if (blockIdx.y == 0) {
    if (tid < 128) hzero[blockIdx.x * 128 + tid] = 0u;
    hcz[blockIdx.x * 1024 + tid] = 0u;
    hcz[blockIdx.x * 1024 + 512 + tid] = 0u;
  }

  f32x4 acc[4];
#pragma unroll
  for (int i = 0; i < 4; i++) acc[i] = (f32x4){0.f, 0.f, 0.f, 0.f};
  const u8* Ah = af + (size_t)t_a * t_stride + L * 16;

  int s_nt = tid >> 6, boff = (tid & 63) * 16;

  {
    uint4 t0 = *(const uint4*)&wfrag[((size_t)(ct0 + s_nt) * nkt2 + 0) * 1024 + boff];
    *(uint4*)&Bs[0][s_nt][boff] = t0;
    if (nkt2 > 1) {
      uint4 t1 = *(const uint4*)&wfrag[((size_t)(ct0 + s_nt) * nkt2 + 1) * 1024 + boff];
      *(uint4*)&Bs[1][s_nt][boff] = t1;
    }
  }
  __syncthreads();

  for (int s = 0; s < nkt2; s++) {
    uint4 nx;
    bool pf = (s + 2 < nkt2);
    if (pf)
      nx = *(const uint4*)&wfrag[((size_t)(ct0 + s_nt) * nkt2 + s + 2) * 1024 + boff];
    int buf = s % 3;
    uint4 a = *(const uint4*)(Ah + (size_t)s * 1024);
    long a0 = mklong(a.x, a.y), a1 = mklong(a.z, a.w);
#pragma unroll
    for (int i = 0; i < 4; i++) {
      uint4 bb = *(const uint4*)&Bs[buf][nt0 + i][L * 16];
      acc[i] = __builtin_amdgcn_mfma_f32_16x16x32_fp8_fp8(a0, mklong(bb.x, bb.y), acc[i], 0, 0, 0);
      acc[i] = __builtin_amdgcn_mfma_f32_16x16x32_fp8_fp8(a1, mklong(bb.z, bb.w), acc[i], 0, 0, 0);
    }
    if (pf) *(uint4*)&Bs[(s + 2) % 3][s_nt][boff] = nx;
    __syncthreads();
  }

  int nq = L >> 4, hl = L & 15;
#pragma unroll
  for (int i = 0; i < 4; i++) {
    int ctg = ct0 + nt0 + i;
    int gcol = (hl >> 2) * HH + ctg * 4 + (hl & 3);
    float bv = bias[gcol];
#pragma unroll
    for (int r = 0; r < 4; r++) {
      int b = nq * 4 + r;
      xz[((size_t)t_a * 16 + b) * G4 + ctg * 16 + hl] = acc[i][r] * DESCALE + bv;
    }
  }
}

// ---------------- one LSTM step, fused, fp8, 16 waves ------------------------
// grid 512 (1 col-tile = 4 hu x 4 gates), 1024 thr = 16 waves (2 pairs each).
__global__ __launch_bounds__(1024, 8) void lstm_step(
    const u8* __restrict__ Ufrag,      // fp8 pair tiles [(ct*32+p)][1024 B]
    const float* __restrict__ xzt,     // [16][8192] permuted cols, fp32
    const u8* __restrict__ hf_in,      // slot t (fp8 A-frags, 32768 B)
    u8* __restrict__ hf_out,           // slot t+1
    const float* __restrict__ hT_in,   // [2048][16] fp32
    float* __restrict__ hT_out,
    float* __restrict__ c,             // [16][2048]
    const int* __restrict__ tokens, int t) {
  __shared__ float red[16][16][16];    // 16 KB
  __shared__ float zs[16][16];
  int tid = threadIdx.x, w = tid >> 6, L = tid & 63;
  int ct = blockIdx.x;

  // early prefetches (hide L2/L3 latency under the MFMA phase)
  float xzv = 0.f;
  if (tid < 256) xzv = xzt[(size_t)(tid >> 4) * G4 + ct * 16 + (tid & 15)];
  float c_old = 0.f, h_old = 0.f;
  int tok = 1;
  if (tid < 64) {
    int b = tid >> 2, hq = tid & 3;
    int hu = ct * 4 + hq;
    c_old = c[(size_t)b * HH + hu];
    h_old = hT_in[(size_t)hu * BB + b];
    tok = tokens[b * TT + t];
  }

  f32x4 acc = {0.f, 0.f, 0.f, 0.f};
  const u8* Ub = Ufrag + ((size_t)ct * 32 + w * 2) * 1024 + L * 16;
  const u8* Hb = hf_in + (size_t)(w * 2) * 1024 + L * 16;

#pragma unroll
  for (int i = 0; i < 2; i++) {
    uint4 u = *(const uint4*)(Ub + i * 1024);
    uint4 h = *(const uint4*)(Hb + i * 1024);
    acc = __builtin_amdgcn_mfma_f32_16x16x32_fp8_fp8(mklong(h.x, h.y), mklong(u.x, u.y), acc, 0, 0, 0);
    acc = __builtin_amdgcn_mfma_f32_16x16x32_fp8_fp8(mklong(h.z, h.w), mklong(u.z, u.w), acc, 0, 0, 0);
  }
#pragma unroll
  for (int r = 0; r < 4; r++) red[w][(L >> 4) * 4 + r][L & 15] = acc[r];
  __syncthreads();

  if (tid < 256) {
    int b = tid >> 4, cl = tid & 15;
    float s = 0.f;
#pragma unroll
    for (int q = 0; q < 16; q++) s += red[q][b][cl];
    zs[b][cl] = s * DESCALE + xzv;
  }
  __syncthreads();

  if (tid < 64) {
    int b = tid >> 2, hq = tid & 3;
    int hu = ct * 4 + hq;
    float z0 = zs[b][0 + hq];
    float z1 = zs[b][4 + hq];
    float z2 = zs[b][8 + hq];
    float z3 = zs[b][12 + hq];
    float ig = 1.f / (1.f + expf(-z0));
    float fg = 1.f / (1.f + expf(-z1));
    float gt = tanhf(z2);
    float og = 1.f / (1.f + expf(-z3));
    float cn = fg * c_old + ig * gt;
    float hn = og * tanhf(cn);
    if (tok == 0) {
      cn = c_old;
      hn = h_old;
    }
    c[(size_t)b * HH + hu] = cn;
    hT_out[(size_t)hu * BB + b] = hn;
    int kt2 = hu >> 5, kk = hu & 31;
    int lane2 = (kk >> 3) * 16 + b, jj = kk & 7;
    hf_out[(size_t)(kt2 >> 1) * 1024 + lane2 * 16 + (kt2 & 1) * 8 + jj] =
        cvt1fp8(hn * SA);
  }
}

// ---------------- head stage 1: K-split partial GEMM (fp32) ------------------
__global__ __launch_bounds__(256) void head_partial(
    const float* __restrict__ XT, const float* __restrict__ W,
    float* __restrict__ partial, int N) {
  __shared__ float xs[2048];  // 128 k x 16 b
  int tid = threadIdx.x;
  int k0 = blockIdx.y * 128;
  const float* src = XT + (size_t)k0 * 16;
  for (int i = tid; i < 2048; i += 256) xs[i] = src[i];
  __syncthreads();
  int kg = tid >> 6, lane = tid & 63;
  int col = blockIdx.x * 64 + lane;
  if (col >= N) return;
  float acc[16];
#pragma unroll
  for (int b = 0; b < 16; b++) acc[b] = 0.f;
  const float* Wp = W + (size_t)(k0 + kg * 32) * N + col;
  const float* xp = xs + kg * 32 * 16;
  for (int kk = 0; kk < 32; kk++) {
    float wv = Wp[(size_t)kk * N];
#pragma unroll
    for (int b = 0; b < 16; b++) acc[b] = fmaf(xp[kk * 16 + b], wv, acc[b]);
  }
  int chunk = blockIdx.y * 4 + kg;
#pragma unroll
  for (int b = 0; b < 16; b++)
    partial[((size_t)chunk * 16 + b) * N + col] = acc[b];
}

// ---------------- head stage 2: reduce 64 chunks + bias ----------------------
__global__ __launch_bounds__(256) void head_reduce(
    const float* __restrict__ partial, const float* __restrict__ bias,
    float* __restrict__ out, int N, int sc, int sb) {
  int i = blockIdx.x * 256 + threadIdx.x;
  if (i >= 16 * N) return;
  int b = i / N, col = i - b * N;
  float s = bias[col];
#pragma unroll 8
  for (int ch = 0; ch < 64; ch++) s += partial[((size_t)ch * 16 + b) * N + col];
  out[(size_t)col * sc + (size_t)b * sb] = s;
}

// ---------------- softmax over rows of [16][1003] ----------------
__global__ __launch_bounds__(256) void softmax_rows(
    const float* __restrict__ logits, float* __restrict__ out, int N) {
  __shared__ float buf[1024];
  __shared__ float wred[4];
  __shared__ float rmax, rsum;
  int b = blockIdx.x, tid = threadIdx.x;
  float m = -1e30f;
  for (int v = tid; v < N; v += 256) {
    float x = logits[(size_t)b * N + v];
    buf[v] = x;
    m = fmaxf(m, x);
  }
  for (int o = 32; o > 0; o >>= 1) m = fmaxf(m, __shfl_down(m, o, 64));
  if ((tid & 63) == 0) wred[tid >> 6] = m;
  __syncthreads();
  if (tid == 0) rmax = fmaxf(fmaxf(wred[0], wred[1]), fmaxf(wred[2], wred[3]));
  __syncthreads();
  float s = 0.f;
  for (int v = tid; v < N; v += 256) {
    float e = expf(buf[v] - rmax);
    buf[v] = e;
    s += e;
  }
  for (int o = 32; o > 0; o >>= 1) s += __shfl_down(s, o, 64);
  if ((tid & 63) == 0) wred[tid >> 6] = s;
  __syncthreads();
  if (tid == 0) rsum = wred[0] + wred[1] + wred[2] + wred[3];
  __syncthreads();
  float inv = 1.f / rsum;
  for (int v = tid; v < N; v += 256) out[(size_t)b * N + v] = buf[v] * inv;
}

extern "C" void kernel_launch(void* const* d_in, const int* in_sizes, int n_in,
                              void* d_out, int out_size, void* d_ws, size_t ws_size,
                              hipStream_t stream) {
  const int*   tokens = (const int*)d_in[0];
  const float* emb  = (const float*)d_in[1];
  const float* W1   = (const float*)d_in[2];
  const float* U1   = (const float*)d_in[3];
  const float* b1   = (const float*)d_in[4];
  const float* W2   = (const float*)d_in[5];
  const float* U2   = (const float*)d_in[6];
  const float* b2   = (const float*)d_in[7];
  const float* W3   = (const float*)d_in[8];
  const float* U3   = (const float*)d_in[9];
  const float* b3   = (const float*)d_in[10];
  const float* Wd1  = (const float*)d_in[11];
  const float* bd1  = (const float*)d_in[12];
  const float* Wd2  = (const float*)d_in[13];
  const float* bd2  = (const float*)d_in[14];
  float* out = (float*)d_out;

  char* base = (char*)d_ws;
  size_t off = 0;
  auto carve = [&](size_t bytes) -> char* {
    char* p = base + off;
    off += (bytes + 255) & ~(size_t)255;
    return p;
  };
  float* xz      = (float*)carve((size_t)TT * BB * G4 * 4);     // 16 MB
  u8*    allhf0  = (u8*)carve(33ull * 32768);                   // 1.08 MB
  u8*    allhf1  = (u8*)carve(33ull * 32768);
  u8*    allhf2  = (u8*)carve(33ull * 32768);
  u8*    xfrag   = (u8*)carve((size_t)TT * 2048);               // 64 KB
  u8*    wf0     = (u8*)carve(512ull * 2 * 1024);               // 1 MB (nkt2=2)
  u8*    uf0     = (u8*)carve(512ull * 64 * 512);               // 16 MB
  u8*    wf1     = (u8*)carve(512ull * 64 * 512);               // 16 MB
  u8*    uf1     = (u8*)carve(512ull * 64 * 512);               // 16 MB
  u8*    wf2     = (u8*)carve(512ull * 64 * 512);               // 16 MB
  u8*    uf2     = (u8*)carve(512ull * 64 * 512);               // 16 MB
  float* hT0     = (float*)carve(2 * HH * BB * 4);              // hT0 + c contiguous
  float* cbuf    = hT0 + HH * BB;
  float* hT1     = (float*)carve(HH * BB * 4);
  float* yT      = (float*)carve(HH * BB * 4);
  float* logits  = (float*)carve(BB * 1024 * 4);
  float* partial = (float*)carve(64ull * 16 * HH * 4);          // 8.4 MB head partials

  u8* allhf[3] = {allhf0, allhf1, allhf2};
  const float* bs[3] = {b1, b2, b3};
  float* hping[2] = {hT0, hT1};
  u8* wfl[3] = {wf0, wf1, wf2};
  u8* ufl[3] = {uf0, uf1, uf2};

  embed_frag<<<dim3(256), 256, 0, stream>>>(tokens, emb, xfrag);
  split_all<<<dim3(162, 32), 256, 0, stream>>>(
      W1, wf0, U1, uf0, W2, wf1, U2, uf1, W3, wf2, U3, uf2);

  for (int layer = 0; layer < 3; layer++) {
    const u8* af;
    int t_stride, nkt2W;
    if (layer == 0) {
      af = xfrag; t_stride = 2048; nkt2W = 2;
    } else {
      af = allhf[layer - 1] + 32768;  // slot 1 == h at t=0
      t_stride = 32768; nkt2W = 32;
    }
    gemm_mfma<<<dim3(64, 8), 512, 0, stream>>>(
        af, t_stride, nkt2W, wfl[layer], bs[layer], xz,
        (unsigned*)allhf[layer], (unsigned*)hT0);
    for (int t = 0; t < TT; t++) {
      lstm_step<<<dim3(512), 1024, 0, stream>>>(
          ufl[layer], xz + (size_t)t * BB * G4,
          allhf[layer] + (size_t)t * 32768, allhf[layer] + (size_t)(t + 1) * 32768,
          hping[t & 1], hping[(t + 1) & 1], cbuf, tokens, t);
    }
  }

  // final h (t=31) is in hT0
  head_partial<<<dim3(HH / 64, 16), 256, 0, stream>>>(hT0, Wd1, partial, HH);
  head_reduce<<<dim3((16 * HH + 255) / 256), 256, 0, stream>>>(partial, bd1, yT, HH, 16, 1);
  head_partial<<<dim3((VV + 63) / 64, 16), 256, 0, stream>>>(yT, Wd2, partial, VV);
  head_reduce<<<dim3((16 * VV + 255) / 256), 256, 0, stream>>>(partial, bd2, logits, VV, 1, VV);
  softmax_rows<<<dim3(BB), 256, 0, stream>>>(logits, out, VV);
}

// Round 19
// 587.326 us; speedup vs baseline: 1.0453x; 1.0453x over previous
//
#include <hip/hip_runtime.h>
#include <hip/hip_bf16.h>
#include <cstddef>

#define BB 16
#define TT 32
#define VV 1003
#define EE 100
#define HH 2048
#define G4 8192  // 4*H

typedef __attribute__((ext_vector_type(4))) float f32x4;
typedef unsigned char u8;

#define SA 64.0f        // A-side (x, h) scale
#define SB 128.0f       // B-side (W, U) scale
#define DESCALE 1.220703125e-4f  // 1/8192

__device__ __forceinline__ unsigned pk_lo(unsigned old, float a, float b) {
  return (unsigned)__builtin_amdgcn_cvt_pk_fp8_f32(a, b, (int)old, false);
}
__device__ __forceinline__ unsigned pk_hi(unsigned old, float a, float b) {
  return (unsigned)__builtin_amdgcn_cvt_pk_fp8_f32(a, b, (int)old, true);
}
__device__ __forceinline__ u8 cvt1fp8(float a) {
  return (u8)(__builtin_amdgcn_cvt_pk_fp8_f32(a, 0.f, 0, false) & 0xff);
}
__device__ __forceinline__ long mklong(unsigned lo, unsigned hi) {
  return (long)(((unsigned long long)hi << 32) | lo);
}

// ---------------- embedding gather -> fp8 A-fragments (pair-interleaved) -----
__global__ __launch_bounds__(256) void embed_frag(
    const int* __restrict__ tokens, const float* __restrict__ emb,
    u8* __restrict__ xf) {
  int i = blockIdx.x * 256 + threadIdx.x;   // 32t * 16b * 128e
  if (i >= TT * BB * 128) return;
  int e = i & 127, b = (i >> 7) & 15, t = i >> 11;
  float v = 0.f;
  if (e < EE) v = emb[(size_t)tokens[b * TT + t] * EE + e] * SA;
  int kt = e >> 5, kk = e & 31;
  int lane = (kk >> 3) * 16 + b, j = kk & 7;
  xf[(size_t)t * 2048 + (size_t)(kt >> 1) * 1024 + lane * 16 + (kt & 1) * 8 + j] =
      cvt1fp8(v);
}

// ---------------- split body: convert-early fp8 transpose in LDS -------------
// LDS bytes: addr(c,row) = c*72 + (c>>6)*8 + row  (c in [0,256), row in [0,64))
// gate-skew (c>>6)*8 breaks the 64-col bank collapse; pad 72 keeps 8B align.
__device__ __forceinline__ void split_body(
    u8* __restrict__ ldb,
    const float* __restrict__ src, u8* __restrict__ dst,
    int Kreal, int nkt2, int pair, int ct0, int tid) {
  int r0 = pair * 64;
#pragma unroll
  for (int p = 0; p < 4; p++) {
    int c4 = tid & 63, rq = p * 4 + (tid >> 6);
    int c = c4 * 4;
    int g = c >> 6;
    int rel = c & 63;
    int row = rq * 4;
    float4 v[4];
#pragma unroll
    for (int i = 0; i < 4; i++) {
      int r = r0 + row + i;
      v[i] = (r < Kreal)
          ? *(const float4*)&src[(size_t)r * G4 + (size_t)g * HH + ct0 * 4 + rel]
          : make_float4(0.f, 0.f, 0.f, 0.f);
    }
#pragma unroll
    for (int j = 0; j < 4; j++) {
      unsigned w = 0;
      w = pk_lo(w, ((const float*)&v[0])[j] * SB, ((const float*)&v[1])[j] * SB);
      w = pk_hi(w, ((const float*)&v[2])[j] * SB, ((const float*)&v[3])[j] * SB);
      int cc = c + j;
      *(unsigned*)&ldb[cc * 72 + g * 8 + row] = w;
    }
  }
  __syncthreads();
  int L = tid & 63;
  int cl = L & 15, gg = cl >> 2, hq = cl & 3;
  int row0 = (L >> 4) * 8;
#pragma unroll
  for (int pass = 0; pass < 4; pass++) {
    int ctr = (tid >> 6) + pass * 4;
    int cc = gg * 64 + ctr * 4 + hq;
    const u8* bp = &ldb[cc * 72 + gg * 8];
    uint2 h0 = *(const uint2*)&bp[row0];
    uint2 h1 = *(const uint2*)&bp[32 + row0];
    *(uint4*)&dst[((size_t)(ct0 + ctr) * nkt2 + pair) * 1024 + L * 16] =
        make_uint4(h0.x, h0.y, h1.x, h1.y);
  }
}

// ---------------- combined W+U split: grid ((nkt2W + 32), 32) ----------------
__global__ __launch_bounds__(256) void split_wu(
    const float* __restrict__ srcW, u8* __restrict__ dstW, int KrealW, int nkt2W,
    const float* __restrict__ srcU, u8* __restrict__ dstU) {
  __shared__ __align__(16) u8 ldb[256 * 72 + 16];   // 18.5 KB
  int tid = threadIdx.x;
  int bx = blockIdx.x, ct0 = blockIdx.y * 16;
  if (bx < nkt2W)
    split_body(ldb, srcW, dstW, KrealW, nkt2W, bx, ct0, tid);
  else
    split_body(ldb, srcU, dstU, HH, 32, bx - nkt2W, ct0, tid);
}

// ---------------- MFMA fp8 GEMM + zero-init of recurrence state --------------
// M-tile 64 (4 t), N-tile 128 (8 ct), stage = 1 pair (BK=64), 3-stage pipeline.
__global__ __launch_bounds__(512) void gemm_mfma(
    const u8* __restrict__ af, int t_stride, int nkt2,
    const u8* __restrict__ wfrag, const float* __restrict__ bias,
    float* __restrict__ xz,
    unsigned* __restrict__ hzero,    // allhf[layer] slot 0: 32768 B
    unsigned* __restrict__ hcz) {    // hT0 + c: 262144 B
  __shared__ __align__(16) u8 Bs[3][8][1024];  // 24 KB
  int tid = threadIdx.x;
  int w = tid >> 6, L = tid & 63;
  int ct0 = blockIdx.x * 8;
  int t_a = blockIdx.y * 4 + (w & 3);
  int nt0 = (w >> 2) * 4;

  if (blockIdx.y == 0) {
    if (tid < 128) hzero[blockIdx.x * 128 + tid] = 0u;
    hcz[blockIdx.x * 1024 + tid] = 0u;
    hcz[blockIdx.x * 1024 + 512 + tid] = 0u;
  }

  f32x4 acc[4];
#pragma unroll
  for (int i = 0; i < 4; i++) acc[i] = (f32x4){0.f, 0.f, 0.f, 0.f};
  const u8* Ah = af + (size_t)t_a * t_stride + L * 16;

  int s_nt = tid >> 6, boff = (tid & 63) * 16;

  {
    uint4 t0 = *(const uint4*)&wfrag[((size_t)(ct0 + s_nt) * nkt2 + 0) * 1024 + boff];
    *(uint4*)&Bs[0][s_nt][boff] = t0;
    if (nkt2 > 1) {
      uint4 t1 = *(const uint4*)&wfrag[((size_t)(ct0 + s_nt) * nkt2 + 1) * 1024 + boff];
      *(uint4*)&Bs[1][s_nt][boff] = t1;
    }
  }
  __syncthreads();

  for (int s = 0; s < nkt2; s++) {
    uint4 nx;
    bool pf = (s + 2 < nkt2);
    if (pf)
      nx = *(const uint4*)&wfrag[((size_t)(ct0 + s_nt) * nkt2 + s + 2) * 1024 + boff];
    int buf = s % 3;
    uint4 a = *(const uint4*)(Ah + (size_t)s * 1024);
    long a0 = mklong(a.x, a.y), a1 = mklong(a.z, a.w);
#pragma unroll
    for (int i = 0; i < 4; i++) {
      uint4 bb = *(const uint4*)&Bs[buf][nt0 + i][L * 16];
      acc[i] = __builtin_amdgcn_mfma_f32_16x16x32_fp8_fp8(a0, mklong(bb.x, bb.y), acc[i], 0, 0, 0);
      acc[i] = __builtin_amdgcn_mfma_f32_16x16x32_fp8_fp8(a1, mklong(bb.z, bb.w), acc[i], 0, 0, 0);
    }
    if (pf) *(uint4*)&Bs[(s + 2) % 3][s_nt][boff] = nx;
    __syncthreads();
  }

  int nq = L >> 4, hl = L & 15;
#pragma unroll
  for (int i = 0; i < 4; i++) {
    int ctg = ct0 + nt0 + i;
    int gcol = (hl >> 2) * HH + ctg * 4 + (hl & 3);
    float bv = bias[gcol];
#pragma unroll
    for (int r = 0; r < 4; r++) {
      int b = nq * 4 + r;
      xz[((size_t)t_a * 16 + b) * G4 + ctg * 16 + hl] = acc[i][r] * DESCALE + bv;
    }
  }
}

// ---------------- one LSTM step, fused, fp8, 16 waves ------------------------
// grid 512 (1 col-tile = 4 hu x 4 gates), 1024 thr = 16 waves (2 pairs each).
__global__ __launch_bounds__(1024, 8) void lstm_step(
    const u8* __restrict__ Ufrag,      // fp8 pair tiles [(ct*32+p)][1024 B]
    const float* __restrict__ xzt,     // [16][8192] permuted cols, fp32
    const u8* __restrict__ hf_in,      // slot t (fp8 A-frags, 32768 B)
    u8* __restrict__ hf_out,           // slot t+1
    const float* __restrict__ hT_in,   // [2048][16] fp32
    float* __restrict__ hT_out,
    float* __restrict__ c,             // [16][2048]
    const int* __restrict__ tokens, int t) {
  __shared__ float red[16][16][16];    // 16 KB
  __shared__ float zs[16][16];
  int tid = threadIdx.x, w = tid >> 6, L = tid & 63;
  int ct = blockIdx.x;

  // early prefetches (hide L2/L3 latency under the MFMA phase)
  float xzv = 0.f;
  if (tid < 256) xzv = xzt[(size_t)(tid >> 4) * G4 + ct * 16 + (tid & 15)];
  float c_old = 0.f, h_old = 0.f;
  int tok = 1;
  if (tid < 64) {
    int b = tid >> 2, hq = tid & 3;
    int hu = ct * 4 + hq;
    c_old = c[(size_t)b * HH + hu];
    h_old = hT_in[(size_t)hu * BB + b];
    tok = tokens[b * TT + t];
  }

  f32x4 acc = {0.f, 0.f, 0.f, 0.f};
  const u8* Ub = Ufrag + ((size_t)ct * 32 + w * 2) * 1024 + L * 16;
  const u8* Hb = hf_in + (size_t)(w * 2) * 1024 + L * 16;

#pragma unroll
  for (int i = 0; i < 2; i++) {
    uint4 u = *(const uint4*)(Ub + i * 1024);
    uint4 h = *(const uint4*)(Hb + i * 1024);
    acc = __builtin_amdgcn_mfma_f32_16x16x32_fp8_fp8(mklong(h.x, h.y), mklong(u.x, u.y), acc, 0, 0, 0);
    acc = __builtin_amdgcn_mfma_f32_16x16x32_fp8_fp8(mklong(h.z, h.w), mklong(u.z, u.w), acc, 0, 0, 0);
  }
#pragma unroll
  for (int r = 0; r < 4; r++) red[w][(L >> 4) * 4 + r][L & 15] = acc[r];
  __syncthreads();

  if (tid < 256) {
    int b = tid >> 4, cl = tid & 15;
    float s = 0.f;
#pragma unroll
    for (int q = 0; q < 16; q++) s += red[q][b][cl];
    zs[b][cl] = s * DESCALE + xzv;
  }
  __syncthreads();

  if (tid < 64) {
    int b = tid >> 2, hq = tid & 3;
    int hu = ct * 4 + hq;
    float z0 = zs[b][0 + hq];
    float z1 = zs[b][4 + hq];
    float z2 = zs[b][8 + hq];
    float z3 = zs[b][12 + hq];
    float ig = 1.f / (1.f + expf(-z0));
    float fg = 1.f / (1.f + expf(-z1));
    float gt = tanhf(z2);
    float og = 1.f / (1.f + expf(-z3));
    float cn = fg * c_old + ig * gt;
    float hn = og * tanhf(cn);
    if (tok == 0) {
      cn = c_old;
      hn = h_old;
    }
    c[(size_t)b * HH + hu] = cn;
    hT_out[(size_t)hu * BB + b] = hn;
    int kt2 = hu >> 5, kk = hu & 31;
    int lane2 = (kk >> 3) * 16 + b, jj = kk & 7;
    hf_out[(size_t)(kt2 >> 1) * 1024 + lane2 * 16 + (kt2 & 1) * 8 + jj] =
        cvt1fp8(hn * SA);
  }
}

// ---------------- head stage 1: K-split partial GEMM (fp32) ------------------
__global__ __launch_bounds__(256) void head_partial(
    const float* __restrict__ XT, const float* __restrict__ W,
    float* __restrict__ partial, int N) {
  __shared__ float xs[2048];  // 128 k x 16 b
  int tid = threadIdx.x;
  int k0 = blockIdx.y * 128;
  const float* src = XT + (size_t)k0 * 16;
  for (int i = tid; i < 2048; i += 256) xs[i] = src[i];
  __syncthreads();
  int kg = tid >> 6, lane = tid & 63;
  int col = blockIdx.x * 64 + lane;
  if (col >= N) return;
  float acc[16];
#pragma unroll
  for (int b = 0; b < 16; b++) acc[b] = 0.f;
  const float* Wp = W + (size_t)(k0 + kg * 32) * N + col;
  const float* xp = xs + kg * 32 * 16;
  for (int kk = 0; kk < 32; kk++) {
    float wv = Wp[(size_t)kk * N];
#pragma unroll
    for (int b = 0; b < 16; b++) acc[b] = fmaf(xp[kk * 16 + b], wv, acc[b]);
  }
  int chunk = blockIdx.y * 4 + kg;
#pragma unroll
  for (int b = 0; b < 16; b++)
    partial[((size_t)chunk * 16 + b) * N + col] = acc[b];
}

// ---------------- head stage 2: reduce 64 chunks + bias ----------------------
__global__ __launch_bounds__(256) void head_reduce(
    const float* __restrict__ partial, const float* __restrict__ bias,
    float* __restrict__ out, int N, int sc, int sb) {
  int i = blockIdx.x * 256 + threadIdx.x;
  if (i >= 16 * N) return;
  int b = i / N, col = i - b * N;
  float s = bias[col];
#pragma unroll 8
  for (int ch = 0; ch < 64; ch++) s += partial[((size_t)ch * 16 + b) * N + col];
  out[(size_t)col * sc + (size_t)b * sb] = s;
}

// ---------------- softmax over rows of [16][1003] ----------------
__global__ __launch_bounds__(256) void softmax_rows(
    const float* __restrict__ logits, float* __restrict__ out, int N) {
  __shared__ float buf[1024];
  __shared__ float wred[4];
  __shared__ float rmax, rsum;
  int b = blockIdx.x, tid = threadIdx.x;
  float m = -1e30f;
  for (int v = tid; v < N; v += 256) {
    float x = logits[(size_t)b * N + v];
    buf[v] = x;
    m = fmaxf(m, x);
  }
  for (int o = 32; o > 0; o >>= 1) m = fmaxf(m, __shfl_down(m, o, 64));
  if ((tid & 63) == 0) wred[tid >> 6] = m;
  __syncthreads();
  if (tid == 0) rmax = fmaxf(fmaxf(wred[0], wred[1]), fmaxf(wred[2], wred[3]));
  __syncthreads();
  float s = 0.f;
  for (int v = tid; v < N; v += 256) {
    float e = expf(buf[v] - rmax);
    buf[v] = e;
    s += e;
  }
  for (int o = 32; o > 0; o >>= 1) s += __shfl_down(s, o, 64);
  if ((tid & 63) == 0) wred[tid >> 6] = s;
  __syncthreads();
  if (tid == 0) rsum = wred[0] + wred[1] + wred[2] + wred[3];
  __syncthreads();
  float inv = 1.f / rsum;
  for (int v = tid; v < N; v += 256) out[(size_t)b * N + v] = buf[v] * inv;
}

extern "C" void kernel_launch(void* const* d_in, const int* in_sizes, int n_in,
                              void* d_out, int out_size, void* d_ws, size_t ws_size,
                              hipStream_t stream) {
  const int*   tokens = (const int*)d_in[0];
  const float* emb  = (const float*)d_in[1];
  const float* W1   = (const float*)d_in[2];
  const float* U1   = (const float*)d_in[3];
  const float* b1   = (const float*)d_in[4];
  const float* W2   = (const float*)d_in[5];
  const float* U2   = (const float*)d_in[6];
  const float* b2   = (const float*)d_in[7];
  const float* W3   = (const float*)d_in[8];
  const float* U3   = (const float*)d_in[9];
  const float* b3   = (const float*)d_in[10];
  const float* Wd1  = (const float*)d_in[11];
  const float* bd1  = (const float*)d_in[12];
  const float* Wd2  = (const float*)d_in[13];
  const float* bd2  = (const float*)d_in[14];
  float* out = (float*)d_out;

  char* base = (char*)d_ws;
  size_t off = 0;
  auto carve = [&](size_t bytes) -> char* {
    char* p = base + off;
    off += (bytes + 255) & ~(size_t)255;
    return p;
  };
  float* xz      = (float*)carve((size_t)TT * BB * G4 * 4);     // 16 MB
  u8*    allhf0  = (u8*)carve(33ull * 32768);                   // 1.08 MB
  u8*    allhf1  = (u8*)carve(33ull * 32768);
  u8*    allhf2  = (u8*)carve(33ull * 32768);
  u8*    xfrag   = (u8*)carve((size_t)TT * 2048);               // 64 KB
  u8*    wfrag   = (u8*)carve(512ull * 64 * 512);               // 16 MB W fp8 frags
  u8*    ufrag   = (u8*)carve(512ull * 64 * 512);               // 16 MB U fp8 frags
  float* hT0     = (float*)carve(2 * HH * BB * 4);              // hT0 + c contiguous
  float* cbuf    = hT0 + HH * BB;
  float* hT1     = (float*)carve(HH * BB * 4);
  float* yT      = (float*)carve(HH * BB * 4);
  float* logits  = (float*)carve(BB * 1024 * 4);
  float* partial = (float*)carve(64ull * 16 * HH * 4);          // 8.4 MB head partials

  u8* allhf[3] = {allhf0, allhf1, allhf2};
  const float* Us[3] = {U1, U2, U3};
  const float* Ws[3] = {W1, W2, W3};
  const float* bs[3] = {b1, b2, b3};
  float* hping[2] = {hT0, hT1};

  embed_frag<<<dim3(256), 256, 0, stream>>>(tokens, emb, xfrag);

  for (int layer = 0; layer < 3; layer++) {
    const u8* af;
    int t_stride, nkt2W;
    if (layer == 0) {
      af = xfrag; t_stride = 2048; nkt2W = 2;
    } else {
      af = allhf[layer - 1] + 32768;  // slot 1 == h at t=0
      t_stride = 32768; nkt2W = 32;
    }
    split_wu<<<dim3(nkt2W + 32, 32), 256, 0, stream>>>(
        Ws[layer], wfrag, (layer == 0) ? EE : HH, nkt2W, Us[layer], ufrag);
    gemm_mfma<<<dim3(64, 8), 512, 0, stream>>>(
        af, t_stride, nkt2W, wfrag, bs[layer], xz,
        (unsigned*)allhf[layer], (unsigned*)hT0);
    for (int t = 0; t < TT; t++) {
      lstm_step<<<dim3(512), 1024, 0, stream>>>(
          ufrag, xz + (size_t)t * BB * G4,
          allhf[layer] + (size_t)t * 32768, allhf[layer] + (size_t)(t + 1) * 32768,
          hping[t & 1], hping[(t + 1) & 1], cbuf, tokens, t);
    }
  }

  // final h (t=31) is in hT0
  head_partial<<<dim3(HH / 64, 16), 256, 0, stream>>>(hT0, Wd1, partial, HH);
  head_reduce<<<dim3((16 * HH + 255) / 256), 256, 0, stream>>>(partial, bd1, yT, HH, 16, 1);
  head_partial<<<dim3((VV + 63) / 64, 16), 256, 0, stream>>>(yT, Wd2, partial, VV);
  head_reduce<<<dim3((16 * VV + 255) / 256), 256, 0, stream>>>(partial, bd2, logits, VV, 1, VV);
  softmax_rows<<<dim3(BB), 256, 0, stream>>>(logits, out, VV);
}

// Round 20
// 580.041 us; speedup vs baseline: 1.0584x; 1.0126x over previous
//
#include <hip/hip_runtime.h>
#include <hip/hip_bf16.h>
#include <cstddef>

#define BB 16
#define TT 32
#define VV 1003
#define EE 100
#define HH 2048
#define G4 8192  // 4*H

typedef __attribute__((ext_vector_type(4))) float f32x4;
typedef unsigned char u8;

#define SA 64.0f        // A-side (x, h) scale
#define SB 128.0f       // B-side (W, U) scale
#define DESCALE 1.220703125e-4f  // 1/8192

__device__ __forceinline__ unsigned pk_lo(unsigned old, float a, float b) {
  return (unsigned)__builtin_amdgcn_cvt_pk_fp8_f32(a, b, (int)old, false);
}
__device__ __forceinline__ unsigned pk_hi(unsigned old, float a, float b) {
  return (unsigned)__builtin_amdgcn_cvt_pk_fp8_f32(a, b, (int)old, true);
}
__device__ __forceinline__ u8 cvt1fp8(float a) {
  return (u8)(__builtin_amdgcn_cvt_pk_fp8_f32(a, 0.f, 0, false) & 0xff);
}
__device__ __forceinline__ long mklong(unsigned lo, unsigned hi) {
  return (long)(((unsigned long long)hi << 32) | lo);
}

// ---------------- embedding gather -> fp8 A-fragments (pair-interleaved) -----
__global__ __launch_bounds__(256) void embed_frag(
    const int* __restrict__ tokens, const float* __restrict__ emb,
    u8* __restrict__ xf) {
  int i = blockIdx.x * 256 + threadIdx.x;   // 32t * 16b * 128e
  if (i >= TT * BB * 128) return;
  int e = i & 127, b = (i >> 7) & 15, t = i >> 11;
  float v = 0.f;
  if (e < EE) v = emb[(size_t)tokens[b * TT + t] * EE + e] * SA;
  int kt = e >> 5, kk = e & 31;
  int lane = (kk >> 3) * 16 + b, j = kk & 7;
  xf[(size_t)t * 2048 + (size_t)(kt >> 1) * 1024 + lane * 16 + (kt & 1) * 8 + j] =
      cvt1fp8(v);
}

// ---------------- split body (256 thr): R15 structure ------------------------
// LDS bytes: addr(c,row) = c*72 + (c>>6)*8 + row  (c in [0,256), row in [0,64))
__device__ __forceinline__ void split_body(
    u8* __restrict__ ldb,
    const float* __restrict__ src, u8* __restrict__ dst,
    int Kreal, int nkt2, int pair, int ct0, int tid) {
  int r0 = pair * 64;
#pragma unroll
  for (int p = 0; p < 4; p++) {
    int c4 = tid & 63, rq = p * 4 + (tid >> 6);
    int c = c4 * 4;
    int g = c >> 6;
    int rel = c & 63;
    int row = rq * 4;
    float4 v[4];
#pragma unroll
    for (int i = 0; i < 4; i++) {
      int r = r0 + row + i;
      v[i] = (r < Kreal)
          ? *(const float4*)&src[(size_t)r * G4 + (size_t)g * HH + ct0 * 4 + rel]
          : make_float4(0.f, 0.f, 0.f, 0.f);
    }
#pragma unroll
    for (int j = 0; j < 4; j++) {
      unsigned w = 0;
      w = pk_lo(w, ((const float*)&v[0])[j] * SB, ((const float*)&v[1])[j] * SB);
      w = pk_hi(w, ((const float*)&v[2])[j] * SB, ((const float*)&v[3])[j] * SB);
      int cc = c + j;
      *(unsigned*)&ldb[cc * 72 + g * 8 + row] = w;
    }
  }
  __syncthreads();
  int L = tid & 63;
  int cl = L & 15, gg = cl >> 2, hq = cl & 3;
  int row0 = (L >> 4) * 8;
#pragma unroll
  for (int pass = 0; pass < 4; pass++) {
    int ctr = (tid >> 6) + pass * 4;
    int cc = gg * 64 + ctr * 4 + hq;
    const u8* bp = &ldb[cc * 72 + gg * 8];
    uint2 h0 = *(const uint2*)&bp[row0];
    uint2 h1 = *(const uint2*)&bp[32 + row0];
    *(uint4*)&dst[((size_t)(ct0 + ctr) * nkt2 + pair) * 1024 + L * 16] =
        make_uint4(h0.x, h0.y, h1.x, h1.y);
  }
}

// ---------------- split body (512 thr): hidden splits, Kreal==HH -------------
__device__ __forceinline__ void split_body_512(
    u8* __restrict__ ldb,
    const float* __restrict__ src, u8* __restrict__ dst,
    int nkt2, int pair, int ct0, int tid) {
  int r0 = pair * 64;
  int c4 = tid & 63;
  int c = c4 * 4;
  int g = c >> 6;
  int rel = c & 63;
  int rg = tid >> 6;            // [0,8): rows rg*8 .. +7
  const float* colbase = src + (size_t)g * HH + ct0 * 4 + rel;
  float4 v[8];
#pragma unroll
  for (int i = 0; i < 8; i++)
    v[i] = *(const float4*)&colbase[(size_t)(r0 + rg * 8 + i) * G4];
#pragma unroll
  for (int j = 0; j < 4; j++) {
    unsigned w0 = 0, w1 = 0;
    w0 = pk_lo(w0, ((const float*)&v[0])[j] * SB, ((const float*)&v[1])[j] * SB);
    w0 = pk_hi(w0, ((const float*)&v[2])[j] * SB, ((const float*)&v[3])[j] * SB);
    w1 = pk_lo(w1, ((const float*)&v[4])[j] * SB, ((const float*)&v[5])[j] * SB);
    w1 = pk_hi(w1, ((const float*)&v[6])[j] * SB, ((const float*)&v[7])[j] * SB);
    int cc = c + j;
    *(unsigned*)&ldb[cc * 72 + g * 8 + rg * 8] = w0;
    *(unsigned*)&ldb[cc * 72 + g * 8 + rg * 8 + 4] = w1;
  }
  __syncthreads();
  int L = tid & 63;
  int cl = L & 15, gg = cl >> 2, hq = cl & 3;
  int row0 = (L >> 4) * 8;
#pragma unroll
  for (int pass = 0; pass < 2; pass++) {
    int ctr = (tid >> 6) + pass * 8;   // [0,16)
    int cc = gg * 64 + ctr * 4 + hq;
    const u8* bp = &ldb[cc * 72 + gg * 8];
    uint2 h0 = *(const uint2*)&bp[row0];
    uint2 h1 = *(const uint2*)&bp[32 + row0];
    *(uint4*)&dst[((size_t)(ct0 + ctr) * nkt2 + pair) * 1024 + L * 16] =
        make_uint4(h0.x, h0.y, h1.x, h1.y);
  }
}

// ---------------- standalone W+U split (layer 0): grid ((nkt2W + 32), 32) ----
__global__ __launch_bounds__(256) void split_wu(
    const float* __restrict__ srcW, u8* __restrict__ dstW, int KrealW, int nkt2W,
    const float* __restrict__ srcU, u8* __restrict__ dstU) {
  __shared__ __align__(16) u8 ldb[256 * 72 + 16];   // 18.5 KB
  int tid = threadIdx.x;
  int bx = blockIdx.x, ct0 = blockIdx.y * 16;
  if (bx < nkt2W)
    split_body(ldb, srcW, dstW, KrealW, nkt2W, bx, ct0, tid);
  else
    split_body(ldb, srcU, dstU, HH, 32, bx - nkt2W, ct0, tid);
}

// ---------------- fused: MFMA fp8 GEMM + next-layer W/U split ----------------
// blocks [0,512): gemm (flattened (64,8): bx=bid&63, by=bid>>6) + state zeroing.
// blocks [512,2560): split of next layer's W (1024 blocks) and U (1024 blocks).
__global__ __launch_bounds__(512) void gemm_split(
    const u8* __restrict__ af, int t_stride, int nkt2,
    const u8* __restrict__ wfrag, const float* __restrict__ bias,
    float* __restrict__ xz,
    unsigned* __restrict__ hzero,    // allhf[layer] slot 0: 32768 B
    unsigned* __restrict__ hcz,      // hT0 + c: 262144 B
    const float* __restrict__ srcWn, u8* __restrict__ dstWn,
    const float* __restrict__ srcUn, u8* __restrict__ dstUn) {
  __shared__ __align__(16) u8 smem[24576];   // gemm 24 KB; split uses 18.5 KB
  int tid = threadIdx.x;
  int bid = blockIdx.x;

  if (bid >= 512) {
    int ext = bid - 512;          // [0,2048)
    int rem = ext & 1023;
    int pair = rem & 31, ct0 = (rem >> 5) * 16;
    if (ext < 1024)
      split_body_512(smem, srcWn, dstWn, 32, pair, ct0, tid);
    else
      split_body_512(smem, srcUn, dstUn, 32, pair, ct0, tid);
    return;
  }

  u8 (*Bs)[8][1024] = (u8 (*)[8][1024])smem;   // [3][8][1024]
  int w = tid >> 6, L = tid & 63;
  int bx = bid & 63, by = bid >> 6;
  int ct0 = bx * 8;
  int t_a = by * 4 + (w & 3);
  int nt0 = (w >> 2) * 4;

  if (by == 0) {
    if (tid < 128) hzero[bx * 128 + tid] = 0u;
    hcz[bx * 1024 + tid] = 0u;
    hcz[bx * 1024 + 512 + tid] = 0u;
  }

  f32x4 acc[4];
#pragma unroll
  for (int i = 0; i < 4; i++) acc[i] = (f32x4){0.f, 0.f, 0.f, 0.f};
  const u8* Ah = af + (size_t)t_a * t_stride + L * 16;

  int s_nt = tid >> 6, boff = (tid & 63) * 16;

  {
    uint4 t0 = *(const uint4*)&wfrag[((size_t)(ct0 + s_nt) * nkt2 + 0) * 1024 + boff];
    *(uint4*)&Bs[0][s_nt][boff] = t0;
    if (nkt2 > 1) {
      uint4 t1 = *(const uint4*)&wfrag[((size_t)(ct0 + s_nt) * nkt2 + 1) * 1024 + boff];
      *(uint4*)&Bs[1][s_nt][boff] = t1;
    }
  }
  __syncthreads();

  for (int s = 0; s < nkt2; s++) {
    uint4 nx;
    bool pf = (s + 2 < nkt2);
    if (pf)
      nx = *(const uint4*)&wfrag[((size_t)(ct0 + s_nt) * nkt2 + s + 2) * 1024 + boff];
    int buf = s % 3;
    uint4 a = *(const uint4*)(Ah + (size_t)s * 1024);
    long a0 = mklong(a.x, a.y), a1 = mklong(a.z, a.w);
#pragma unroll
    for (int i = 0; i < 4; i++) {
      uint4 bb = *(const uint4*)&Bs[buf][nt0 + i][L * 16];
      acc[i] = __builtin_amdgcn_mfma_f32_16x16x32_fp8_fp8(a0, mklong(bb.x, bb.y), acc[i], 0, 0, 0);
      acc[i] = __builtin_amdgcn_mfma_f32_16x16x32_fp8_fp8(a1, mklong(bb.z, bb.w), acc[i], 0, 0, 0);
    }
    if (pf) *(uint4*)&Bs[(s + 2) % 3][s_nt][boff] = nx;
    __syncthreads();
  }

  int nq = L >> 4, hl = L & 15;
#pragma unroll
  for (int i = 0; i < 4; i++) {
    int ctg = ct0 + nt0 + i;
    int gcol = (hl >> 2) * HH + ctg * 4 + (hl & 3);
    float bv = bias[gcol];
#pragma unroll
    for (int r = 0; r < 4; r++) {
      int b = nq * 4 + r;
      xz[((size_t)t_a * 16 + b) * G4 + ctg * 16 + hl] = acc[i][r] * DESCALE + bv;
    }
  }
}

// ---------------- one LSTM step, fused, fp8, 16 waves ------------------------
// grid 512 (1 col-tile = 4 hu x 4 gates), 1024 thr = 16 waves (2 pairs each).
__global__ __launch_bounds__(1024, 8) void lstm_step(
    const u8* __restrict__ Ufrag,      // fp8 pair tiles [(ct*32+p)][1024 B]
    const float* __restrict__ xzt,     // [16][8192] permuted cols, fp32
    const u8* __restrict__ hf_in,      // slot t (fp8 A-frags, 32768 B)
    u8* __restrict__ hf_out,           // slot t+1
    const float* __restrict__ hT_in,   // [2048][16] fp32
    float* __restrict__ hT_out,
    float* __restrict__ c,             // [16][2048]
    const int* __restrict__ tokens, int t) {
  __shared__ float red[16][16][16];    // 16 KB
  __shared__ float zs[16][16];
  int tid = threadIdx.x, w = tid >> 6, L = tid & 63;
  int ct = blockIdx.x;

  // early prefetches (hide L2/L3 latency under the MFMA phase)
  float xzv = 0.f;
  if (tid < 256) xzv = xzt[(size_t)(tid >> 4) * G4 + ct * 16 + (tid & 15)];
  float c_old = 0.f, h_old = 0.f;
  int tok = 1;
  if (tid < 64) {
    int b = tid >> 2, hq = tid & 3;
    int hu = ct * 4 + hq;
    c_old = c[(size_t)b * HH + hu];
    h_old = hT_in[(size_t)hu * BB + b];
    tok = tokens[b * TT + t];
  }

  f32x4 acc = {0.f, 0.f, 0.f, 0.f};
  const u8* Ub = Ufrag + ((size_t)ct * 32 + w * 2) * 1024 + L * 16;
  const u8* Hb = hf_in + (size_t)(w * 2) * 1024 + L * 16;

#pragma unroll
  for (int i = 0; i < 2; i++) {
    uint4 u = *(const uint4*)(Ub + i * 1024);
    uint4 h = *(const uint4*)(Hb + i * 1024);
    acc = __builtin_amdgcn_mfma_f32_16x16x32_fp8_fp8(mklong(h.x, h.y), mklong(u.x, u.y), acc, 0, 0, 0);
    acc = __builtin_amdgcn_mfma_f32_16x16x32_fp8_fp8(mklong(h.z, h.w), mklong(u.z, u.w), acc, 0, 0, 0);
  }
#pragma unroll
  for (int r = 0; r < 4; r++) red[w][(L >> 4) * 4 + r][L & 15] = acc[r];
  __syncthreads();

  if (tid < 256) {
    int b = tid >> 4, cl = tid & 15;
    float s = 0.f;
#pragma unroll
    for (int q = 0; q < 16; q++) s += red[q][b][cl];
    zs[b][cl] = s * DESCALE + xzv;
  }
  __syncthreads();

  if (tid < 64) {
    int b = tid >> 2, hq = tid & 3;
    int hu = ct * 4 + hq;
    float z0 = zs[b][0 + hq];
    float z1 = zs[b][4 + hq];
    float z2 = zs[b][8 + hq];
    float z3 = zs[b][12 + hq];
    float ig = 1.f / (1.f + expf(-z0));
    float fg = 1.f / (1.f + expf(-z1));
    float gt = tanhf(z2);
    float og = 1.f / (1.f + expf(-z3));
    float cn = fg * c_old + ig * gt;
    float hn = og * tanhf(cn);
    if (tok == 0) {
      cn = c_old;
      hn = h_old;
    }
    c[(size_t)b * HH + hu] = cn;
    hT_out[(size_t)hu * BB + b] = hn;
    int kt2 = hu >> 5, kk = hu & 31;
    int lane2 = (kk >> 3) * 16 + b, jj = kk & 7;
    hf_out[(size_t)(kt2 >> 1) * 1024 + lane2 * 16 + (kt2 & 1) * 8 + jj] =
        cvt1fp8(hn * SA);
  }
}

// ---------------- head stage 1: K-split partial GEMM (fp32) ------------------
__global__ __launch_bounds__(256) void head_partial(
    const float* __restrict__ XT, const float* __restrict__ W,
    float* __restrict__ partial, int N) {
  __shared__ float xs[2048];  // 128 k x 16 b
  int tid = threadIdx.x;
  int k0 = blockIdx.y * 128;
  const float* src = XT + (size_t)k0 * 16;
  for (int i = tid; i < 2048; i += 256) xs[i] = src[i];
  __syncthreads();
  int kg = tid >> 6, lane = tid & 63;
  int col = blockIdx.x * 64 + lane;
  if (col >= N) return;
  float acc[16];
#pragma unroll
  for (int b = 0; b < 16; b++) acc[b] = 0.f;
  const float* Wp = W + (size_t)(k0 + kg * 32) * N + col;
  const float* xp = xs + kg * 32 * 16;
  for (int kk = 0; kk < 32; kk++) {
    float wv = Wp[(size_t)kk * N];
#pragma unroll
    for (int b = 0; b < 16; b++) acc[b] = fmaf(xp[kk * 16 + b], wv, acc[b]);
  }
  int chunk = blockIdx.y * 4 + kg;
#pragma unroll
  for (int b = 0; b < 16; b++)
    partial[((size_t)chunk * 16 + b) * N + col] = acc[b];
}

// ---------------- head stage 2: reduce 64 chunks + bias ----------------------
__global__ __launch_bounds__(256) void head_reduce(
    const float* __restrict__ partial, const float* __restrict__ bias,
    float* __restrict__ out, int N, int sc, int sb) {
  int i = blockIdx.x * 256 + threadIdx.x;
  if (i >= 16 * N) return;
  int b = i / N, col = i - b * N;
  float s = bias[col];
#pragma unroll 8
  for (int ch = 0; ch < 64; ch++) s += partial[((size_t)ch * 16 + b) * N + col];
  out[(size_t)col * sc + (size_t)b * sb] = s;
}

// ---------------- softmax over rows of [16][1003] ----------------
__global__ __launch_bounds__(256) void softmax_rows(
    const float* __restrict__ logits, float* __restrict__ out, int N) {
  __shared__ float buf[1024];
  __shared__ float wred[4];
  __shared__ float rmax, rsum;
  int b = blockIdx.x, tid = threadIdx.x;
  float m = -1e30f;
  for (int v = tid; v < N; v += 256) {
    float x = logits[(size_t)b * N + v];
    buf[v] = x;
    m = fmaxf(m, x);
  }
  for (int o = 32; o > 0; o >>= 1) m = fmaxf(m, __shfl_down(m, o, 64));
  if ((tid & 63) == 0) wred[tid >> 6] = m;
  __syncthreads();
  if (tid == 0) rmax = fmaxf(fmaxf(wred[0], wred[1]), fmaxf(wred[2], wred[3]));
  __syncthreads();
  float s = 0.f;
  for (int v = tid; v < N; v += 256) {
    float e = expf(buf[v] - rmax);
    buf[v] = e;
    s += e;
  }
  for (int o = 32; o > 0; o >>= 1) s += __shfl_down(s, o, 64);
  if ((tid & 63) == 0) wred[tid >> 6] = s;
  __syncthreads();
  if (tid == 0) rsum = wred[0] + wred[1] + wred[2] + wred[3];
  __syncthreads();
  float inv = 1.f / rsum;
  for (int v = tid; v < N; v += 256) out[(size_t)b * N + v] = buf[v] * inv;
}

extern "C" void kernel_launch(void* const* d_in, const int* in_sizes, int n_in,
                              void* d_out, int out_size, void* d_ws, size_t ws_size,
                              hipStream_t stream) {
  const int*   tokens = (const int*)d_in[0];
  const float* emb  = (const float*)d_in[1];
  const float* W1   = (const float*)d_in[2];
  const float* U1   = (const float*)d_in[3];
  const float* b1   = (const float*)d_in[4];
  const float* W2   = (const float*)d_in[5];
  const float* U2   = (const float*)d_in[6];
  const float* b2   = (const float*)d_in[7];
  const float* W3   = (const float*)d_in[8];
  const float* U3   = (const float*)d_in[9];
  const float* b3   = (const float*)d_in[10];
  const float* Wd1  = (const float*)d_in[11];
  const float* bd1  = (const float*)d_in[12];
  const float* Wd2  = (const float*)d_in[13];
  const float* bd2  = (const float*)d_in[14];
  float* out = (float*)d_out;

  char* base = (char*)d_ws;
  size_t off = 0;
  auto carve = [&](size_t bytes) -> char* {
    char* p = base + off;
    off += (bytes + 255) & ~(size_t)255;
    return p;
  };
  float* xz      = (float*)carve((size_t)TT * BB * G4 * 4);     // 16 MB
  u8*    allhf0  = (u8*)carve(33ull * 32768);                   // 1.08 MB
  u8*    allhf1  = (u8*)carve(33ull * 32768);
  u8*    allhf2  = (u8*)carve(33ull * 32768);
  u8*    xfrag   = (u8*)carve((size_t)TT * 2048);               // 64 KB
  u8*    wfA     = (u8*)carve(512ull * 64 * 512);               // 16 MB
  u8*    ufA     = (u8*)carve(512ull * 64 * 512);               // 16 MB
  u8*    wfB     = (u8*)carve(512ull * 64 * 512);               // 16 MB
  u8*    ufB     = (u8*)carve(512ull * 64 * 512);               // 16 MB
  float* hT0     = (float*)carve(2 * HH * BB * 4);              // hT0 + c contiguous
  float* cbuf    = hT0 + HH * BB;
  float* hT1     = (float*)carve(HH * BB * 4);
  float* yT      = (float*)carve(HH * BB * 4);
  float* logits  = (float*)carve(BB * 1024 * 4);
  float* partial = (float*)carve(64ull * 16 * HH * 4);          // 8.4 MB head partials

  u8* allhf[3] = {allhf0, allhf1, allhf2};
  const float* bs[3] = {b1, b2, b3};
  float* hping[2] = {hT0, hT1};
  // frag buffer sets: layer 0 -> A, layer 1 -> B, layer 2 -> A
  u8* wfl[3] = {wfA, wfB, wfA};
  u8* ufl[3] = {ufA, ufB, ufA};
  const float* Wnext[3] = {W2, W3, nullptr};
  const float* Unext[3] = {U2, U3, nullptr};

  embed_frag<<<dim3(256), 256, 0, stream>>>(tokens, emb, xfrag);
  // standalone split for layer 0 (W1 K=100 -> nkt2=2)
  split_wu<<<dim3(2 + 32, 32), 256, 0, stream>>>(W1, wfA, EE, 2, U1, ufA);

  for (int layer = 0; layer < 3; layer++) {
    const u8* af;
    int t_stride, nkt2W;
    if (layer == 0) {
      af = xfrag; t_stride = 2048; nkt2W = 2;
    } else {
      af = allhf[layer - 1] + 32768;  // slot 1 == h at t=0
      t_stride = 32768; nkt2W = 32;
    }
    int grid = (layer < 2) ? 2560 : 512;  // fold next layer's split
    gemm_split<<<dim3(grid), 512, 0, stream>>>(
        af, t_stride, nkt2W, wfl[layer], bs[layer], xz,
        (unsigned*)allhf[layer], (unsigned*)hT0,
        Wnext[layer], wfl[layer + 1 < 3 ? layer + 1 : 0],
        Unext[layer], ufl[layer + 1 < 3 ? layer + 1 : 0]);
    for (int t = 0; t < TT; t++) {
      lstm_step<<<dim3(512), 1024, 0, stream>>>(
          ufl[layer], xz + (size_t)t * BB * G4,
          allhf[layer] + (size_t)t * 32768, allhf[layer] + (size_t)(t + 1) * 32768,
          hping[t & 1], hping[(t + 1) & 1], cbuf, tokens, t);
    }
  }

  // final h (t=31) is in hT0
  head_partial<<<dim3(HH / 64, 16), 256, 0, stream>>>(hT0, Wd1, partial, HH);
  head_reduce<<<dim3((16 * HH + 255) / 256), 256, 0, stream>>>(partial, bd1, yT, HH, 16, 1);
  head_partial<<<dim3((VV + 63) / 64, 16), 256, 0, stream>>>(yT, Wd2, partial, VV);
  head_reduce<<<dim3((16 * VV + 255) / 256), 256, 0, stream>>>(partial, bd2, logits, VV, 1, VV);
  softmax_rows<<<dim3(BB), 256, 0, stream>>>(logits, out, VV);
}

// Round 21
// 575.940 us; speedup vs baseline: 1.0660x; 1.0071x over previous
//
#include <hip/hip_runtime.h>
#include <hip/hip_bf16.h>
#include <cstddef>

#define BB 16
#define TT 32
#define VV 1003
#define EE 100
#define HH 2048
#define G4 8192  // 4*H

typedef __attribute__((ext_vector_type(4))) float f32x4;
typedef unsigned char u8;

#define SA 64.0f        // A-side (x, h) scale
#define SB 128.0f       // B-side (W, U) scale
#define DESCALE 1.220703125e-4f  // 1/8192

__device__ __forceinline__ unsigned pk_lo(unsigned old, float a, float b) {
  return (unsigned)__builtin_amdgcn_cvt_pk_fp8_f32(a, b, (int)old, false);
}
__device__ __forceinline__ unsigned pk_hi(unsigned old, float a, float b) {
  return (unsigned)__builtin_amdgcn_cvt_pk_fp8_f32(a, b, (int)old, true);
}
__device__ __forceinline__ u8 cvt1fp8(float a) {
  return (u8)(__builtin_amdgcn_cvt_pk_fp8_f32(a, 0.f, 0, false) & 0xff);
}
__device__ __forceinline__ long mklong(unsigned lo, unsigned hi) {
  return (long)(((unsigned long long)hi << 32) | lo);
}

// ---------------- split body (256 thr) ---------------------------------------
// LDS bytes: addr(c,row) = c*72 + (c>>6)*8 + row  (c in [0,256), row in [0,64))
__device__ __forceinline__ void split_body(
    u8* __restrict__ ldb,
    const float* __restrict__ src, u8* __restrict__ dst,
    int Kreal, int nkt2, int pair, int ct0, int tid) {
  int r0 = pair * 64;
#pragma unroll
  for (int p = 0; p < 4; p++) {
    int c4 = tid & 63, rq = p * 4 + (tid >> 6);
    int c = c4 * 4;
    int g = c >> 6;
    int rel = c & 63;
    int row = rq * 4;
    float4 v[4];
#pragma unroll
    for (int i = 0; i < 4; i++) {
      int r = r0 + row + i;
      v[i] = (r < Kreal)
          ? *(const float4*)&src[(size_t)r * G4 + (size_t)g * HH + ct0 * 4 + rel]
          : make_float4(0.f, 0.f, 0.f, 0.f);
    }
#pragma unroll
    for (int j = 0; j < 4; j++) {
      unsigned w = 0;
      w = pk_lo(w, ((const float*)&v[0])[j] * SB, ((const float*)&v[1])[j] * SB);
      w = pk_hi(w, ((const float*)&v[2])[j] * SB, ((const float*)&v[3])[j] * SB);
      int cc = c + j;
      *(unsigned*)&ldb[cc * 72 + g * 8 + row] = w;
    }
  }
  __syncthreads();
  int L = tid & 63;
  int cl = L & 15, gg = cl >> 2, hq = cl & 3;
  int row0 = (L >> 4) * 8;
#pragma unroll
  for (int pass = 0; pass < 4; pass++) {
    int ctr = (tid >> 6) + pass * 4;
    int cc = gg * 64 + ctr * 4 + hq;
    const u8* bp = &ldb[cc * 72 + gg * 8];
    uint2 h0 = *(const uint2*)&bp[row0];
    uint2 h1 = *(const uint2*)&bp[32 + row0];
    *(uint4*)&dst[((size_t)(ct0 + ctr) * nkt2 + pair) * 1024 + L * 16] =
        make_uint4(h0.x, h0.y, h1.x, h1.y);
  }
}

// ---------------- split body (512 thr): hidden splits, Kreal==HH -------------
__device__ __forceinline__ void split_body_512(
    u8* __restrict__ ldb,
    const float* __restrict__ src, u8* __restrict__ dst,
    int nkt2, int pair, int ct0, int tid) {
  int r0 = pair * 64;
  int c4 = tid & 63;
  int c = c4 * 4;
  int g = c >> 6;
  int rel = c & 63;
  int rg = tid >> 6;            // [0,8): rows rg*8 .. +7
  const float* colbase = src + (size_t)g * HH + ct0 * 4 + rel;
  float4 v[8];
#pragma unroll
  for (int i = 0; i < 8; i++)
    v[i] = *(const float4*)&colbase[(size_t)(r0 + rg * 8 + i) * G4];
#pragma unroll
  for (int j = 0; j < 4; j++) {
    unsigned w0 = 0, w1 = 0;
    w0 = pk_lo(w0, ((const float*)&v[0])[j] * SB, ((const float*)&v[1])[j] * SB);
    w0 = pk_hi(w0, ((const float*)&v[2])[j] * SB, ((const float*)&v[3])[j] * SB);
    w1 = pk_lo(w1, ((const float*)&v[4])[j] * SB, ((const float*)&v[5])[j] * SB);
    w1 = pk_hi(w1, ((const float*)&v[6])[j] * SB, ((const float*)&v[7])[j] * SB);
    int cc = c + j;
    *(unsigned*)&ldb[cc * 72 + g * 8 + rg * 8] = w0;
    *(unsigned*)&ldb[cc * 72 + g * 8 + rg * 8 + 4] = w1;
  }
  __syncthreads();
  int L = tid & 63;
  int cl = L & 15, gg = cl >> 2, hq = cl & 3;
  int row0 = (L >> 4) * 8;
#pragma unroll
  for (int pass = 0; pass < 2; pass++) {
    int ctr = (tid >> 6) + pass * 8;   // [0,16)
    int cc = gg * 64 + ctr * 4 + hq;
    const u8* bp = &ldb[cc * 72 + gg * 8];
    uint2 h0 = *(const uint2*)&bp[row0];
    uint2 h1 = *(const uint2*)&bp[32 + row0];
    *(uint4*)&dst[((size_t)(ct0 + ctr) * nkt2 + pair) * 1024 + L * 16] =
        make_uint4(h0.x, h0.y, h1.x, h1.y);
  }
}

// ---------------- prep0: W1 split (64 blocks) + embedding (256 blocks) -------
__global__ __launch_bounds__(256) void prep0(
    const int* __restrict__ tokens, const float* __restrict__ emb,
    u8* __restrict__ xf,
    const float* __restrict__ W1, u8* __restrict__ wfA) {
  __shared__ __align__(16) u8 ldb[256 * 72 + 16];   // 18.5 KB
  int tid = threadIdx.x;
  int bid = blockIdx.x;
  if (bid < 64) {
    split_body(ldb, W1, wfA, EE, 2, bid >> 5, (bid & 31) * 16, tid);
    return;
  }
  int i = (bid - 64) * 256 + tid;   // 32t * 16b * 128e
  if (i >= TT * BB * 128) return;
  int e = i & 127, b = (i >> 7) & 15, t = i >> 11;
  float v = 0.f;
  if (e < EE) v = emb[(size_t)tokens[b * TT + t] * EE + e] * SA;
  int kt = e >> 5, kk = e & 31;
  int lane = (kk >> 3) * 16 + b, j = kk & 7;
  xf[(size_t)t * 2048 + (size_t)(kt >> 1) * 1024 + lane * 16 + (kt & 1) * 8 + j] =
      cvt1fp8(v);
}

// ---------------- fused: MFMA fp8 GEMM + up to 3 pending W/U splits ----------
// blocks [0,512): gemm (bx=bid&63, by=bid>>6) + state zeroing.
// blocks [512, 512+1024*n): split unit u = (bid-512)>>10 -> (s_u, d_u).
__global__ __launch_bounds__(512) void gemm_split(
    const u8* __restrict__ af, int t_stride, int nkt2,
    const u8* __restrict__ wfrag, const float* __restrict__ bias,
    float* __restrict__ xz,
    unsigned* __restrict__ hzero,    // allhf[layer] slot 0: 32768 B
    unsigned* __restrict__ hcz,      // hT0 + c: 262144 B
    const float* __restrict__ s0, u8* __restrict__ d0,
    const float* __restrict__ s1, u8* __restrict__ d1,
    const float* __restrict__ s2, u8* __restrict__ d2) {
  __shared__ __align__(16) u8 smem[24576];   // gemm 24 KB; split uses 18.5 KB
  int tid = threadIdx.x;
  int bid = blockIdx.x;

  if (bid >= 512) {
    int ext = bid - 512;
    int unit = ext >> 10;         // 0..2
    int rem = ext & 1023;
    const float* s = (unit == 0) ? s0 : (unit == 1) ? s1 : s2;
    u8* d = (unit == 0) ? d0 : (unit == 1) ? d1 : d2;
    split_body_512(smem, s, d, 32, rem & 31, (rem >> 5) * 16, tid);
    return;
  }

  u8 (*Bs)[8][1024] = (u8 (*)[8][1024])smem;   // [3][8][1024]
  int w = tid >> 6, L = tid & 63;
  int bx = bid & 63, by = bid >> 6;
  int ct0 = bx * 8;
  int t_a = by * 4 + (w & 3);
  int nt0 = (w >> 2) * 4;

  if (by == 0) {
    if (tid < 128) hzero[bx * 128 + tid] = 0u;
    hcz[bx * 1024 + tid] = 0u;
    hcz[bx * 1024 + 512 + tid] = 0u;
  }

  f32x4 acc[4];
#pragma unroll
  for (int i = 0; i < 4; i++) acc[i] = (f32x4){0.f, 0.f, 0.f, 0.f};
  const u8* Ah = af + (size_t)t_a * t_stride + L * 16;

  int s_nt = tid >> 6, boff = (tid & 63) * 16;

  {
    uint4 t0 = *(const uint4*)&wfrag[((size_t)(ct0 + s_nt) * nkt2 + 0) * 1024 + boff];
    *(uint4*)&Bs[0][s_nt][boff] = t0;
    if (nkt2 > 1) {
      uint4 t1 = *(const uint4*)&wfrag[((size_t)(ct0 + s_nt) * nkt2 + 1) * 1024 + boff];
      *(uint4*)&Bs[1][s_nt][boff] = t1;
    }
  }
  __syncthreads();

  for (int s = 0; s < nkt2; s++) {
    uint4 nx;
    bool pf = (s + 2 < nkt2);
    if (pf)
      nx = *(const uint4*)&wfrag[((size_t)(ct0 + s_nt) * nkt2 + s + 2) * 1024 + boff];
    int buf = s % 3;
    uint4 a = *(const uint4*)(Ah + (size_t)s * 1024);
    long a0 = mklong(a.x, a.y), a1 = mklong(a.z, a.w);
#pragma unroll
    for (int i = 0; i < 4; i++) {
      uint4 bb = *(const uint4*)&Bs[buf][nt0 + i][L * 16];
      acc[i] = __builtin_amdgcn_mfma_f32_16x16x32_fp8_fp8(a0, mklong(bb.x, bb.y), acc[i], 0, 0, 0);
      acc[i] = __builtin_amdgcn_mfma_f32_16x16x32_fp8_fp8(a1, mklong(bb.z, bb.w), acc[i], 0, 0, 0);
    }
    if (pf) *(uint4*)&Bs[(s + 2) % 3][s_nt][boff] = nx;
    __syncthreads();
  }

  int nq = L >> 4, hl = L & 15;
#pragma unroll
  for (int i = 0; i < 4; i++) {
    int ctg = ct0 + nt0 + i;
    int gcol = (hl >> 2) * HH + ctg * 4 + (hl & 3);
    float bv = bias[gcol];
#pragma unroll
    for (int r = 0; r < 4; r++) {
      int b = nq * 4 + r;
      xz[((size_t)t_a * 16 + b) * G4 + ctg * 16 + hl] = acc[i][r] * DESCALE + bv;
    }
  }
}

// ---------------- one LSTM step, fused, fp8, 16 waves ------------------------
// grid 512 (1 col-tile = 4 hu x 4 gates), 1024 thr = 16 waves (2 pairs each).
__global__ __launch_bounds__(1024, 8) void lstm_step(
    const u8* __restrict__ Ufrag,      // fp8 pair tiles [(ct*32+p)][1024 B]
    const float* __restrict__ xzt,     // [16][8192] permuted cols, fp32
    const u8* __restrict__ hf_in,      // slot t (fp8 A-frags, 32768 B)
    u8* __restrict__ hf_out,           // slot t+1
    const float* __restrict__ hT_in,   // [2048][16] fp32
    float* __restrict__ hT_out,
    float* __restrict__ c,             // [16][2048]
    const int* __restrict__ tokens, int t) {
  __shared__ float red[16][16][16];    // 16 KB
  __shared__ float zs[16][16];
  int tid = threadIdx.x, w = tid >> 6, L = tid & 63;
  int ct = blockIdx.x;

  // early prefetches (hide L2/L3 latency under the MFMA phase)
  float xzv = 0.f;
  if (tid < 256) xzv = xzt[(size_t)(tid >> 4) * G4 + ct * 16 + (tid & 15)];
  float c_old = 0.f, h_old = 0.f;
  int tok = 1;
  if (tid < 64) {
    int b = tid >> 2, hq = tid & 3;
    int hu = ct * 4 + hq;
    c_old = c[(size_t)b * HH + hu];
    h_old = hT_in[(size_t)hu * BB + b];
    tok = tokens[b * TT + t];
  }

  f32x4 acc = {0.f, 0.f, 0.f, 0.f};
  const u8* Ub = Ufrag + ((size_t)ct * 32 + w * 2) * 1024 + L * 16;
  const u8* Hb = hf_in + (size_t)(w * 2) * 1024 + L * 16;

#pragma unroll
  for (int i = 0; i < 2; i++) {
    uint4 u = *(const uint4*)(Ub + i * 1024);
    uint4 h = *(const uint4*)(Hb + i * 1024);
    acc = __builtin_amdgcn_mfma_f32_16x16x32_fp8_fp8(mklong(h.x, h.y), mklong(u.x, u.y), acc, 0, 0, 0);
    acc = __builtin_amdgcn_mfma_f32_16x16x32_fp8_fp8(mklong(h.z, h.w), mklong(u.z, u.w), acc, 0, 0, 0);
  }
#pragma unroll
  for (int r = 0; r < 4; r++) red[w][(L >> 4) * 4 + r][L & 15] = acc[r];
  __syncthreads();

  if (tid < 256) {
    int b = tid >> 4, cl = tid & 15;
    float s = 0.f;
#pragma unroll
    for (int q = 0; q < 16; q++) s += red[q][b][cl];
    zs[b][cl] = s * DESCALE + xzv;
  }
  __syncthreads();

  if (tid < 64) {
    int b = tid >> 2, hq = tid & 3;
    int hu = ct * 4 + hq;
    float z0 = zs[b][0 + hq];
    float z1 = zs[b][4 + hq];
    float z2 = zs[b][8 + hq];
    float z3 = zs[b][12 + hq];
    float ig = 1.f / (1.f + expf(-z0));
    float fg = 1.f / (1.f + expf(-z1));
    float gt = tanhf(z2);
    float og = 1.f / (1.f + expf(-z3));
    float cn = fg * c_old + ig * gt;
    float hn = og * tanhf(cn);
    if (tok == 0) {
      cn = c_old;
      hn = h_old;
    }
    c[(size_t)b * HH + hu] = cn;
    hT_out[(size_t)hu * BB + b] = hn;
    int kt2 = hu >> 5, kk = hu & 31;
    int lane2 = (kk >> 3) * 16 + b, jj = kk & 7;
    hf_out[(size_t)(kt2 >> 1) * 1024 + lane2 * 16 + (kt2 & 1) * 8 + jj] =
        cvt1fp8(hn * SA);
  }
}

// ---------------- head stage 1: K-split partial GEMM (fp32) ------------------
__global__ __launch_bounds__(256) void head_partial(
    const float* __restrict__ XT, const float* __restrict__ W,
    float* __restrict__ partial, int N) {
  __shared__ float xs[2048];  // 128 k x 16 b
  int tid = threadIdx.x;
  int k0 = blockIdx.y * 128;
  const float* src = XT + (size_t)k0 * 16;
  for (int i = tid; i < 2048; i += 256) xs[i] = src[i];
  __syncthreads();
  int kg = tid >> 6, lane = tid & 63;
  int col = blockIdx.x * 64 + lane;
  if (col >= N) return;
  float acc[16];
#pragma unroll
  for (int b = 0; b < 16; b++) acc[b] = 0.f;
  const float* Wp = W + (size_t)(k0 + kg * 32) * N + col;
  const float* xp = xs + kg * 32 * 16;
  for (int kk = 0; kk < 32; kk++) {
    float wv = Wp[(size_t)kk * N];
#pragma unroll
    for (int b = 0; b < 16; b++) acc[b] = fmaf(xp[kk * 16 + b], wv, acc[b]);
  }
  int chunk = blockIdx.y * 4 + kg;
#pragma unroll
  for (int b = 0; b < 16; b++)
    partial[((size_t)chunk * 16 + b) * N + col] = acc[b];
}

// ---------------- head stage 2: reduce 64 chunks + bias ----------------------
__global__ __launch_bounds__(256) void head_reduce(
    const float* __restrict__ partial, const float* __restrict__ bias,
    float* __restrict__ out, int N, int sc, int sb) {
  int i = blockIdx.x * 256 + threadIdx.x;
  if (i >= 16 * N) return;
  int b = i / N, col = i - b * N;
  float s = bias[col];
#pragma unroll 8
  for (int ch = 0; ch < 64; ch++) s += partial[((size_t)ch * 16 + b) * N + col];
  out[(size_t)col * sc + (size_t)b * sb] = s;
}

// ---------------- softmax over rows of [16][1003] ----------------
__global__ __launch_bounds__(256) void softmax_rows(
    const float* __restrict__ logits, float* __restrict__ out, int N) {
  __shared__ float buf[1024];
  __shared__ float wred[4];
  __shared__ float rmax, rsum;
  int b = blockIdx.x, tid = threadIdx.x;
  float m = -1e30f;
  for (int v = tid; v < N; v += 256) {
    float x = logits[(size_t)b * N + v];
    buf[v] = x;
    m = fmaxf(m, x);
  }
  for (int o = 32; o > 0; o >>= 1) m = fmaxf(m, __shfl_down(m, o, 64));
  if ((tid & 63) == 0) wred[tid >> 6] = m;
  __syncthreads();
  if (tid == 0) rmax = fmaxf(fmaxf(wred[0], wred[1]), fmaxf(wred[2], wred[3]));
  __syncthreads();
  float s = 0.f;
  for (int v = tid; v < N; v += 256) {
    float e = expf(buf[v] - rmax);
    buf[v] = e;
    s += e;
  }
  for (int o = 32; o > 0; o >>= 1) s += __shfl_down(s, o, 64);
  if ((tid & 63) == 0) wred[tid >> 6] = s;
  __syncthreads();
  if (tid == 0) rsum = wred[0] + wred[1] + wred[2] + wred[3];
  __syncthreads();
  float inv = 1.f / rsum;
  for (int v = tid; v < N; v += 256) out[(size_t)b * N + v] = buf[v] * inv;
}

extern "C" void kernel_launch(void* const* d_in, const int* in_sizes, int n_in,
                              void* d_out, int out_size, void* d_ws, size_t ws_size,
                              hipStream_t stream) {
  const int*   tokens = (const int*)d_in[0];
  const float* emb  = (const float*)d_in[1];
  const float* W1   = (const float*)d_in[2];
  const float* U1   = (const float*)d_in[3];
  const float* b1   = (const float*)d_in[4];
  const float* W2   = (const float*)d_in[5];
  const float* U2   = (const float*)d_in[6];
  const float* b2   = (const float*)d_in[7];
  const float* W3   = (const float*)d_in[8];
  const float* U3   = (const float*)d_in[9];
  const float* b3   = (const float*)d_in[10];
  const float* Wd1  = (const float*)d_in[11];
  const float* bd1  = (const float*)d_in[12];
  const float* Wd2  = (const float*)d_in[13];
  const float* bd2  = (const float*)d_in[14];
  float* out = (float*)d_out;

  char* base = (char*)d_ws;
  size_t off = 0;
  auto carve = [&](size_t bytes) -> char* {
    char* p = base + off;
    off += (bytes + 255) & ~(size_t)255;
    return p;
  };
  float* xz      = (float*)carve((size_t)TT * BB * G4 * 4);     // 16 MB
  u8*    allhf0  = (u8*)carve(33ull * 32768);                   // 1.08 MB
  u8*    allhf1  = (u8*)carve(33ull * 32768);
  u8*    allhf2  = (u8*)carve(33ull * 32768);
  u8*    xfrag   = (u8*)carve((size_t)TT * 2048);               // 64 KB
  u8*    wfA     = (u8*)carve(512ull * 64 * 512);               // 16 MB
  u8*    ufA     = (u8*)carve(512ull * 64 * 512);               // 16 MB
  u8*    wfB     = (u8*)carve(512ull * 64 * 512);               // 16 MB
  u8*    ufB     = (u8*)carve(512ull * 64 * 512);               // 16 MB
  float* hT0     = (float*)carve(2 * HH * BB * 4);              // hT0 + c contiguous
  float* cbuf    = hT0 + HH * BB;
  float* hT1     = (float*)carve(HH * BB * 4);
  float* yT      = (float*)carve(HH * BB * 4);
  float* logits  = (float*)carve(BB * 1024 * 4);
  float* partial = (float*)carve(64ull * 16 * HH * 4);          // 8.4 MB head partials

  u8* allhf[3] = {allhf0, allhf1, allhf2};
  const float* bs[3] = {b1, b2, b3};
  float* hping[2] = {hT0, hT1};
  // frag sets: l0 -> A (W1 via prep0, U1 via gemm_split0), l1 -> B, l2 -> A
  u8* wfl[3] = {wfA, wfB, wfA};
  u8* ufl[3] = {ufA, ufB, ufA};

  prep0<<<dim3(320), 256, 0, stream>>>(tokens, emb, xfrag, W1, wfA);

  for (int layer = 0; layer < 3; layer++) {
    const u8* af;
    int t_stride, nkt2W;
    if (layer == 0) {
      af = xfrag; t_stride = 2048; nkt2W = 2;
    } else {
      af = allhf[layer - 1] + 32768;  // slot 1 == h at t=0
      t_stride = 32768; nkt2W = 32;
    }
    int grid;
    const float *s0 = nullptr, *s1 = nullptr, *s2 = nullptr;
    u8 *d0 = nullptr, *d1 = nullptr, *d2 = nullptr;
    if (layer == 0) {
      grid = 512 + 3 * 1024;
      s0 = U1; d0 = ufA;
      s1 = W2; d1 = wfB;
      s2 = U2; d2 = ufB;
    } else if (layer == 1) {
      grid = 512 + 2 * 1024;
      s0 = W3; d0 = wfA;
      s1 = U3; d1 = ufA;
    } else {
      grid = 512;
    }
    gemm_split<<<dim3(grid), 512, 0, stream>>>(
        af, t_stride, nkt2W, wfl[layer], bs[layer], xz,
        (unsigned*)allhf[layer], (unsigned*)hT0,
        s0, d0, s1, d1, s2, d2);
    for (int t = 0; t < TT; t++) {
      lstm_step<<<dim3(512), 1024, 0, stream>>>(
          ufl[layer], xz + (size_t)t * BB * G4,
          allhf[layer] + (size_t)t * 32768, allhf[layer] + (size_t)(t + 1) * 32768,
          hping[t & 1], hping[(t + 1) & 1], cbuf, tokens, t);
    }
  }

  // final h (t=31) is in hT0
  head_partial<<<dim3(HH / 64, 16), 256, 0, stream>>>(hT0, Wd1, partial, HH);
  head_reduce<<<dim3((16 * HH + 255) / 256), 256, 0, stream>>>(partial, bd1, yT, HH, 16, 1);
  head_partial<<<dim3((VV + 63) / 64, 16), 256, 0, stream>>>(yT, Wd2, partial, VV);
  head_reduce<<<dim3((16 * VV + 255) / 256), 256, 0, stream>>>(partial, bd2, logits, VV, 1, VV);
  softmax_rows<<<dim3(BB), 256, 0, stream>>>(logits, out, VV);
}